// Round 5
// baseline (647.427 us; speedup 1.0000x reference)
//
#include <hip/hip_runtime.h>
#include <hip/hip_bf16.h>

typedef __bf16 bf16;
typedef __attribute__((ext_vector_type(8))) __bf16 bf16x8;
typedef __attribute__((ext_vector_type(4))) float f32x4;

#define GLOAD_LDS16(g, l)                                                        \
    __builtin_amdgcn_global_load_lds(                                            \
        (const __attribute__((address_space(1))) void*)(g),                      \
        (__attribute__((address_space(3))) void*)(l), 16, 0, 0)

#define WAITV(n) asm volatile("s_waitcnt vmcnt(" #n ")" ::: "memory")

// ---------------- fp32 -> bf16 conversion (vectorized, grid-stride) ----------------
__global__ __launch_bounds__(256) void cvt_f32_bf16(
    const float* __restrict__ src, bf16* __restrict__ dst, int n16)
{
    int idx = blockIdx.x * 256 + threadIdx.x;
    const int stride = gridDim.x * 256;
    for (int i = idx; i < n16; i += stride) {
        const float* p = src + (size_t)i * 16;
        f32x4 a = *(const f32x4*)p;
        f32x4 b = *(const f32x4*)(p + 4);
        f32x4 c = *(const f32x4*)(p + 8);
        f32x4 d = *(const f32x4*)(p + 12);
        bf16x8 h0, h1;
#pragma unroll
        for (int j = 0; j < 4; ++j) {
            h0[j] = (bf16)a[j]; h0[4 + j] = (bf16)b[j];
            h1[j] = (bf16)c[j]; h1[4 + j] = (bf16)d[j];
        }
        bf16* q = dst + (size_t)i * 16;
        *(bf16x8*)q = h0;
        *(bf16x8*)(q + 8) = h1;
    }
}

// ------------- deep-pipelined GEMM: C[M][BN-grid] = A[M][K] * B[N][K]^T + bias -------------
// BM=256, BK=32, 8 waves (512 thr), 4 LDS buffers, counted vmcnt (never 0 mid-loop),
// raw s_barrier (1 per K-tile, no compiler vmcnt(0) drain).
// LDS XOR swizzle: linear gload_lds dest + pre-swizzled global source + swizzled ds_read
// (involution: physical slot p holds logical p^(row&3); reader reads p=hi^(row&3) -> hi).
template <int BN_, int OUT_BF16>
__global__ __launch_bounds__(512, 2) void gemm256(
    const bf16* __restrict__ A, const bf16* __restrict__ B,
    const float* __restrict__ bias, void* __restrict__ Cout,
    int K, int ldc)
{
    constexpr int BM = 256;
    constexpr int WN = BN_ / 64;          // waves along N: 4 (BN=256) | 2 (BN=128)
    constexpr int WM = 8 / WN;            // waves along M: 2 | 4
    constexpr int MR = (BM / WM) / 16;    // 8 | 4 m-fragments per wave
    constexpr int NR = 4;                 // 4 n-fragments per wave (64 cols)
    constexpr int ASZ = BM * 32;          // 16 KB per buffer
    constexpr int BSZ = BN_ * 32;         // 16 | 8 KB per buffer

    __shared__ bf16 As[4][ASZ];
    __shared__ bf16 Bs[4][BSZ];

    const int tid  = threadIdx.x;
    const int w    = tid >> 6, lane = tid & 63;
    const int lo   = lane & 15, hi = lane >> 4;
    const int wr   = w / WN, wc = w % WN;
    const int brow = blockIdx.y * BM;
    const int bcol = blockIdx.x * BN_;

    // stage-source per-lane offsets: chunk = 16 rows x 64B; lane -> row l>>2, swizzled col
    const int srow = lane >> 2;
    const int scol = ((lane & 3) ^ ((lane >> 2) & 3)) * 8;   // pre-swizzled global col (elems)

    f32x4 acc[MR][NR];
#pragma unroll
    for (int m = 0; m < MR; ++m)
#pragma unroll
        for (int n = 0; n < NR; ++n)
            acc[m][n] = (f32x4){0.f, 0.f, 0.f, 0.f};

    auto STAGE = [&](int tt) {
        const int nb = tt & 3;
        const int k0 = tt * 32;
#pragma unroll
        for (int i = 0; i < 2; ++i) {   // A: 16 chunks, wave w owns {2w, 2w+1}
            const int c = w * 2 + i;
            GLOAD_LDS16(A + (size_t)(brow + c * 16 + srow) * K + k0 + scol, &As[nb][c * 512]);
        }
        if constexpr (BN_ == 256) {     // B: 16 chunks, wave w owns {2w, 2w+1}
#pragma unroll
            for (int i = 0; i < 2; ++i) {
                const int c = w * 2 + i;
                GLOAD_LDS16(B + (size_t)(bcol + c * 16 + srow) * K + k0 + scol, &Bs[nb][c * 512]);
            }
        } else {                        // B: 8 chunks, wave w owns {w}
            GLOAD_LDS16(B + (size_t)(bcol + w * 16 + srow) * K + k0 + scol, &Bs[nb][w * 512]);
        }
    };

    const int nt = K / 32;  // 128 for K=4096
    STAGE(0); STAGE(1); STAGE(2);
    if constexpr (BN_ == 256) WAITV(8); else WAITV(6);   // tile 0 landed
    __builtin_amdgcn_s_barrier();

    for (int t = 0; t < nt; ++t) {
        if (t + 3 < nt) STAGE(t + 3);   // overwrites buf of tile t-1 (all waves past it)
        const int nb = t & 3;

        bf16x8 af[MR], bfr[NR];
#pragma unroll
        for (int m = 0; m < MR; ++m) {
            const int row = wr * (BM / WM) + m * 16 + lo;
            af[m] = *(const bf16x8*)&As[nb][row * 32 + ((hi ^ (lo & 3)) * 8)];
        }
#pragma unroll
        for (int n = 0; n < NR; ++n) {
            const int row = wc * 64 + n * 16 + lo;
            bfr[n] = *(const bf16x8*)&Bs[nb][row * 32 + ((hi ^ (lo & 3)) * 8)];
        }

        __builtin_amdgcn_s_setprio(1);
#pragma unroll
        for (int m = 0; m < MR; ++m)
#pragma unroll
            for (int n = 0; n < NR; ++n)
                acc[m][n] = __builtin_amdgcn_mfma_f32_16x16x32_bf16(af[m], bfr[n], acc[m][n], 0, 0, 0);
        __builtin_amdgcn_s_setprio(0);

        // counted waits: retire exactly tile t+1 (issued 3 iters ago); never drain mid-loop
        if constexpr (BN_ == 256) {
            if (t + 3 < nt)       WAITV(8);
            else if (t + 3 == nt) WAITV(4);
            else if (t + 2 == nt) WAITV(0);
        } else {
            if (t + 3 < nt)       WAITV(6);
            else if (t + 3 == nt) WAITV(3);
            else if (t + 2 == nt) WAITV(0);
        }
        __builtin_amdgcn_s_barrier();
    }

    // epilogue: C/D layout row=(lane>>4)*4+r, col=lane&15
#pragma unroll
    for (int m = 0; m < MR; ++m) {
        const int row = brow + wr * (BM / WM) + m * 16 + hi * 4;
#pragma unroll
        for (int n = 0; n < NR; ++n) {
            const int col = bcol + wc * 64 + n * 16 + lo;
            const float bv = bias[col];
#pragma unroll
            for (int r = 0; r < 4; ++r) {
                const float v = acc[m][n][r] + bv;
                if (OUT_BF16)
                    ((bf16*)Cout)[(size_t)(row + r) * ldc + col] = (bf16)v;
                else
                    ((float*)Cout)[(size_t)(row + r) * ldc + col] = v;
            }
        }
    }
}

// ---------------- MFMA flash attention: causal + ALiBi, bf16 in/out (round-4, verified) ----------------
__global__ __launch_bounds__(512) void attn_mfma(
    const bf16* __restrict__ qkv, bf16* __restrict__ attn_out)
{
    const int S = 2048, QKV = 12288, D = 4096, HD = 128;
    const int bid = blockIdx.x;
    const int h   = bid & 31;
    const int qi  = 15 - (bid >> 5);
    const int q0  = qi * 128;
    const int tid = threadIdx.x;
    const int w    = tid >> 6, lane = tid & 63;
    const int lo   = lane & 15, hi = lane >> 4;
    const int qbase = q0 + w * 16;

    __shared__ bf16 Ks[64 * 128];       // [kv][d], elem idx ^ ((kv&7)<<3)
    __shared__ bf16 Vs[128 * 72];       // [d][kv], rows padded 64->72
    __shared__ bf16 Ps[8 * 16 * 72];    // per-wave [q][kv] P tile, stride 72

    const float scale = 0.08838834764831845f;
    const float slope = exp2f(-0.25f * (float)(h + 1));

    bf16x8 qfrag[4];
#pragma unroll
    for (int ds = 0; ds < 4; ++ds)
        qfrag[ds] = *(const bf16x8*)(qkv + (size_t)(qbase + lo) * QKV + h * HD + ds * 32 + hi * 8);

    f32x4 o[8];
#pragma unroll
    for (int dt = 0; dt < 8; ++dt) o[dt] = (f32x4){0.f, 0.f, 0.f, 0.f};
    float mrow[4] = {-1e30f, -1e30f, -1e30f, -1e30f};
    float lrow[4] = {0.f, 0.f, 0.f, 0.f};

    const int krow = tid >> 3;
    const int kch  = tid & 7;
    const int vd   = tid & 127;
    const int vkh  = tid >> 7;

    const int ntile = (q0 + 128) / 64;
    for (int t = 0; t < ntile; ++t) {
        const int kv0 = t * 64;
        {
            const bf16* kp = qkv + (size_t)(kv0 + krow) * QKV + D + h * HD + kch * 16;
            bf16x8 k0 = *(const bf16x8*)kp;
            bf16x8 k1 = *(const bf16x8*)(kp + 8);
            const int kb  = krow * 128 + kch * 16;
            const int swz = (krow & 7) << 3;
            *(bf16x8*)&Ks[kb ^ swz]       = k0;
            *(bf16x8*)&Ks[(kb + 8) ^ swz] = k1;
        }
        {
            const bf16* vp = qkv + (size_t)(kv0 + vkh * 16) * QKV + 2 * D + h * HD + vd;
            bf16x8 v0, v1;
#pragma unroll
            for (int j = 0; j < 8; ++j) {
                v0[j] = vp[(size_t)j * QKV];
                v1[j] = vp[(size_t)(8 + j) * QKV];
            }
            *(bf16x8*)&Vs[vd * 72 + vkh * 16]     = v0;
            *(bf16x8*)&Vs[vd * 72 + vkh * 16 + 8] = v1;
        }
        __syncthreads();

        if (kv0 <= qbase + 15) {
            f32x4 c[4];
#pragma unroll
            for (int j = 0; j < 4; ++j) c[j] = (f32x4){0.f, 0.f, 0.f, 0.f};
            __builtin_amdgcn_s_setprio(1);
#pragma unroll
            for (int ds = 0; ds < 4; ++ds) {
#pragma unroll
                for (int j = 0; j < 4; ++j) {
                    const int r = j * 16 + lo;
                    bf16x8 b = *(const bf16x8*)&Ks[(r * 128 + ds * 32 + hi * 8) ^ ((r & 7) << 3)];
                    c[j] = __builtin_amdgcn_mfma_f32_16x16x32_bf16(qfrag[ds], b, c[j], 0, 0, 0);
                }
            }
            __builtin_amdgcn_s_setprio(0);
#pragma unroll
            for (int r = 0; r < 4; ++r) {
                const int q = qbase + hi * 4 + r;
                float s[4];
#pragma unroll
                for (int j = 0; j < 4; ++j) {
                    const int ki = kv0 + j * 16 + lo;
                    s[j] = c[j][r] * scale + slope * (float)(ki - (S - 1));
                    if (ki > q) s[j] = -1e30f;
                }
                float tm = fmaxf(fmaxf(s[0], s[1]), fmaxf(s[2], s[3]));
                tm = fmaxf(tm, __shfl_xor(tm, 1));
                tm = fmaxf(tm, __shfl_xor(tm, 2));
                tm = fmaxf(tm, __shfl_xor(tm, 4));
                tm = fmaxf(tm, __shfl_xor(tm, 8));
                const float mnew = fmaxf(mrow[r], tm);
                const float cr = __expf(mrow[r] - mnew);
                float p[4], ps = 0.f;
#pragma unroll
                for (int j = 0; j < 4; ++j) { p[j] = __expf(s[j] - mnew); ps += p[j]; }
                ps += __shfl_xor(ps, 1);
                ps += __shfl_xor(ps, 2);
                ps += __shfl_xor(ps, 4);
                ps += __shfl_xor(ps, 8);
                lrow[r] = lrow[r] * cr + ps;
                mrow[r] = mnew;
#pragma unroll
                for (int dt = 0; dt < 8; ++dt) o[dt][r] *= cr;
#pragma unroll
                for (int j = 0; j < 4; ++j)
                    Ps[w * 1152 + (hi * 4 + r) * 72 + j * 16 + lo] = (bf16)p[j];
            }
            bf16x8 pa0 = *(const bf16x8*)&Ps[w * 1152 + lo * 72 + hi * 8];
            bf16x8 pa1 = *(const bf16x8*)&Ps[w * 1152 + lo * 72 + 32 + hi * 8];
            __builtin_amdgcn_s_setprio(1);
#pragma unroll
            for (int dt = 0; dt < 8; ++dt) {
                bf16x8 bv0 = *(const bf16x8*)&Vs[(dt * 16 + lo) * 72 + hi * 8];
                bf16x8 bv1 = *(const bf16x8*)&Vs[(dt * 16 + lo) * 72 + 32 + hi * 8];
                o[dt] = __builtin_amdgcn_mfma_f32_16x16x32_bf16(pa0, bv0, o[dt], 0, 0, 0);
                o[dt] = __builtin_amdgcn_mfma_f32_16x16x32_bf16(pa1, bv1, o[dt], 0, 0, 0);
            }
            __builtin_amdgcn_s_setprio(0);
        }
        __syncthreads();
    }

#pragma unroll
    for (int r = 0; r < 4; ++r) {
        const float inv = 1.0f / lrow[r];
        const int q = qbase + hi * 4 + r;
        bf16* op = attn_out + (size_t)q * D + h * HD;
#pragma unroll
        for (int dt = 0; dt < 8; ++dt)
            op[dt * 16 + lo] = (bf16)(o[dt][r] * inv);
    }
}

extern "C" void kernel_launch(void* const* d_in, const int* in_sizes, int n_in,
                              void* d_out, int out_size, void* d_ws, size_t ws_size,
                              hipStream_t stream) {
    const int S = 2048, D = 4096, QKV = 12288;
    const int NH = 6144;
    const float* x     = (const float*)d_in[0];
    const float* w_qkv = (const float*)d_in[1];
    const float* b_qkv = (const float*)d_in[2];
    const float* w_out = (const float*)d_in[3];
    const float* b_out = (const float*)d_in[4];
    float* out = (float*)d_out;

    char* ws = (char*)d_ws;
    const size_t need_full = (size_t)S * D * 2 + (size_t)QKV * D * 2 + (size_t)S * QKV * 2;

    if (ws_size >= need_full) {
        // full-weight path: QKV GEMM as one launch, BN=128 -> 768 blocks (3 full CU rounds)
        bf16* xb    = (bf16*)ws;                                    // [2048][4096]
        bf16* attnb = xb;                                           // reuse after xb dead
        bf16* wqb   = (bf16*)(ws + (size_t)S * D * 2);              // [12288][4096]
        bf16* wob   = wqb;                                          // reuse after wqb dead
        bf16* qkvb  = (bf16*)(ws + (size_t)S * D * 2 + (size_t)QKV * D * 2);  // [2048][12288]

        cvt_f32_bf16<<<2048, 256, 0, stream>>>(x, xb, S * D / 16);
        cvt_f32_bf16<<<4096, 256, 0, stream>>>(w_qkv, wqb, QKV * D / 16);
        gemm256<128, 1><<<dim3(QKV / 128, S / 256), 512, 0, stream>>>(xb, wqb, b_qkv, qkvb, D, QKV);
        attn_mfma<<<512, 512, 0, stream>>>(qkvb, attnb);
        cvt_f32_bf16<<<2048, 256, 0, stream>>>(w_out, wob, D * D / 16);
        gemm256<128, 0><<<dim3(D / 128, S / 256), 512, 0, stream>>>(attnb, wob, b_out, out, D, D);
    } else {
        // halves path (peak 117.4 MB): QKV in two N-halves sharing one weight buffer
        bf16* xb    = (bf16*)ws;
        bf16* attnb = xb;
        bf16* wb    = (bf16*)(ws + (size_t)S * D * 2);              // [6144][4096]
        bf16* wob   = wb;
        bf16* qkvb  = (bf16*)(ws + (size_t)S * D * 2 + (size_t)NH * D * 2);

        cvt_f32_bf16<<<2048, 256, 0, stream>>>(x, xb, S * D / 16);
        cvt_f32_bf16<<<2048, 256, 0, stream>>>(w_qkv, wb, NH * D / 16);
        gemm256<256, 1><<<dim3(NH / 256, S / 256), 512, 0, stream>>>(xb, wb, b_qkv, qkvb, D, QKV);
        cvt_f32_bf16<<<2048, 256, 0, stream>>>(w_qkv + (size_t)NH * D, wb, NH * D / 16);
        gemm256<256, 1><<<dim3(NH / 256, S / 256), 512, 0, stream>>>(xb, wb, b_qkv + NH, qkvb + NH, D, QKV);
        attn_mfma<<<512, 512, 0, stream>>>(qkvb, attnb);
        cvt_f32_bf16<<<2048, 256, 0, stream>>>(w_out, wob, D * D / 16);
        gemm256<128, 0><<<dim3(D / 128, S / 256), 512, 0, stream>>>(attnb, wob, b_out, out, D, D);
    }
}

// Round 6
// 484.305 us; speedup vs baseline: 1.3368x; 1.3368x over previous
//
#include <hip/hip_runtime.h>
#include <hip/hip_bf16.h>

typedef __bf16 bf16;
typedef __attribute__((ext_vector_type(8))) __bf16 bf16x8;
typedef __attribute__((ext_vector_type(4))) float f32x4;

#define GLOAD_LDS16(g, l)                                                        \
    __builtin_amdgcn_global_load_lds(                                            \
        (const __attribute__((address_space(1))) void*)(g),                      \
        (__attribute__((address_space(3))) void*)(l), 16, 0, 0)

// ---------------- fp32 -> bf16 conversion (vectorized, grid-stride) ----------------
__global__ __launch_bounds__(256) void cvt_f32_bf16(
    const float* __restrict__ src, bf16* __restrict__ dst, int n16)
{
    int idx = blockIdx.x * 256 + threadIdx.x;
    const int stride = gridDim.x * 256;
    for (int i = idx; i < n16; i += stride) {
        const float* p = src + (size_t)i * 16;
        f32x4 a = *(const f32x4*)p;
        f32x4 b = *(const f32x4*)(p + 4);
        f32x4 c = *(const f32x4*)(p + 8);
        f32x4 d = *(const f32x4*)(p + 12);
        bf16x8 h0, h1;
#pragma unroll
        for (int j = 0; j < 4; ++j) {
            h0[j] = (bf16)a[j]; h0[4 + j] = (bf16)b[j];
            h1[j] = (bf16)c[j]; h1[4 + j] = (bf16)d[j];
        }
        bf16* q = dst + (size_t)i * 16;
        *(bf16x8*)q = h0;
        *(bf16x8*)(q + 8) = h1;
    }
}

// ------- m97-structure GEMM, BK=64 + 8-slot XOR swizzle: C = A[M][K]*B[N][K]^T + bias -------
// 128x128 tile, 4 waves, LDS 2x16KB linear (global_load_lds w16), two barriers per 64-K step.
// Swizzle (rule #21 both-sides): physical 16B-slot s of row r holds global chunk s^(r&7);
// staged via pre-swizzled global col, read at slot (kk*4+hi)^(row&7) -> 2-way banks (free).
template <int OUT_BF16>
__global__ __launch_bounds__(256) void gemm_glds(
    const bf16* __restrict__ A, const bf16* __restrict__ B,
    const float* __restrict__ bias, void* __restrict__ Cout,
    int K, int ldc)
{
    __shared__ bf16 As[128 * 64];
    __shared__ bf16 Bs[128 * 64];

    const int tid  = threadIdx.x;
    const int wv   = tid >> 6, lane = tid & 63;
    const int lo   = lane & 15, hi = lane >> 4;
    const int wr   = wv >> 1, wc = wv & 1;
    const int brow = blockIdx.y * 128;
    const int bcol = blockIdx.x * 128;

    f32x4 acc[4][4];
#pragma unroll
    for (int m = 0; m < 4; ++m)
#pragma unroll
        for (int n = 0; n < 4; ++n)
            acc[m][n] = (f32x4){0.f, 0.f, 0.f, 0.f};

    // staging: chunk c (1KB) covers rows c*8..c*8+7; lane -> row c*8+(lane>>3),
    // phys slot lane&7; global col = ((lane&7) ^ (lane>>3)) * 8 (row&7 == lane>>3).
    const int srow = lane >> 3;                       // 0..7
    const int scol = ((lane & 7) ^ (lane >> 3)) * 8;  // pre-swizzled col (elems)

    for (int k0 = 0; k0 < K; k0 += 64) {
#pragma unroll
        for (int i = 0; i < 4; ++i) {   // wave owns chunks wv*4 .. wv*4+3 (A and B)
            const int c = wv * 4 + i;
            GLOAD_LDS16(A + (size_t)(brow + c * 8 + srow) * K + k0 + scol, &As[c * 512]);
            GLOAD_LDS16(B + (size_t)(bcol + c * 8 + srow) * K + k0 + scol, &Bs[c * 512]);
        }
        __syncthreads();

#pragma unroll
        for (int kk = 0; kk < 2; ++kk) {
            bf16x8 af[4], bf[4];
#pragma unroll
            for (int m = 0; m < 4; ++m) {
                const int row = wr * 64 + m * 16 + lo;
                af[m] = *(const bf16x8*)&As[row * 64 + (((kk * 4 + hi) ^ (lo & 7)) * 8)];
            }
#pragma unroll
            for (int n = 0; n < 4; ++n) {
                const int row = wc * 64 + n * 16 + lo;
                bf[n] = *(const bf16x8*)&Bs[row * 64 + (((kk * 4 + hi) ^ (lo & 7)) * 8)];
            }
#pragma unroll
            for (int m = 0; m < 4; ++m)
#pragma unroll
                for (int n = 0; n < 4; ++n)
                    acc[m][n] = __builtin_amdgcn_mfma_f32_16x16x32_bf16(af[m], bf[n], acc[m][n], 0, 0, 0);
        }
        __syncthreads();
    }

    // epilogue: C/D layout row=(lane>>4)*4+r, col=lane&15
#pragma unroll
    for (int m = 0; m < 4; ++m) {
        const int row = brow + wr * 64 + m * 16 + hi * 4;
#pragma unroll
        for (int n = 0; n < 4; ++n) {
            const int col = bcol + wc * 64 + n * 16 + lo;
            const float bv = bias[col];
#pragma unroll
            for (int r = 0; r < 4; ++r) {
                const float v = acc[m][n][r] + bv;
                if (OUT_BF16)
                    ((bf16*)Cout)[(size_t)(row + r) * ldc + col] = (bf16)v;
                else
                    ((float*)Cout)[(size_t)(row + r) * ldc + col] = v;
            }
        }
    }
}

// ---------------- MFMA flash attention: causal + ALiBi, bf16 in/out ----------------
// 1D grid 512 blocks x 512 thr (8 waves); head = bid&31, qi descending. q-tile 128, KVBLK 64.
// K: [64][128] XOR-swizzled, vector-staged. V: transposed [128][72]; staged by
// (d-pair, kv-oct) owners: 8 u32 global loads -> 2 ds_write_b128. Read path unchanged.
__global__ __launch_bounds__(512) void attn_mfma(
    const bf16* __restrict__ qkv, bf16* __restrict__ attn_out)
{
    const int S = 2048, QKV = 12288, D = 4096, HD = 128;
    const int bid = blockIdx.x;
    const int h   = bid & 31;
    const int qi  = 15 - (bid >> 5);
    const int q0  = qi * 128;
    const int tid = threadIdx.x;
    const int w    = tid >> 6, lane = tid & 63;
    const int lo   = lane & 15, hi = lane >> 4;
    const int qbase = q0 + w * 16;

    __shared__ bf16 Ks[64 * 128];       // [kv][d], elem idx ^ ((kv&7)<<3)
    __shared__ bf16 Vs[128 * 72];       // [d][kv], rows padded 64->72
    __shared__ bf16 Ps[8 * 16 * 72];    // per-wave [q][kv] P tile, stride 72

    const float scale = 0.08838834764831845f;
    const float slope = exp2f(-0.25f * (float)(h + 1));

    bf16x8 qfrag[4];
#pragma unroll
    for (int ds = 0; ds < 4; ++ds)
        qfrag[ds] = *(const bf16x8*)(qkv + (size_t)(qbase + lo) * QKV + h * HD + ds * 32 + hi * 8);

    f32x4 o[8];
#pragma unroll
    for (int dt = 0; dt < 8; ++dt) o[dt] = (f32x4){0.f, 0.f, 0.f, 0.f};
    float mrow[4] = {-1e30f, -1e30f, -1e30f, -1e30f};
    float lrow[4] = {0.f, 0.f, 0.f, 0.f};

    const int krow = tid >> 3;        // K: kv row 0..63
    const int kch  = tid & 7;         // K: 16-elem d-chunk
    const int vp2  = tid & 63;        // V: d-pair (d = 2*vp2)
    const int voct = tid >> 6;        // V: kv octet 0..7

    const int ntile = (q0 + 128) / 64;
    for (int t = 0; t < ntile; ++t) {
        const int kv0 = t * 64;
        // ---- K stage (vectorized, swizzled) ----
        {
            const bf16* kp = qkv + (size_t)(kv0 + krow) * QKV + D + h * HD + kch * 16;
            bf16x8 k0 = *(const bf16x8*)kp;
            bf16x8 k1 = *(const bf16x8*)(kp + 8);
            const int kb  = krow * 128 + kch * 16;
            const int swz = (krow & 7) << 3;
            *(bf16x8*)&Ks[kb ^ swz]       = k0;
            *(bf16x8*)&Ks[(kb + 8) ^ swz] = k1;
        }
        // ---- V stage transposed: thread owns (d={2p,2p+1}, kv=oct*8..+7) ----
        {
            const bf16* vp = qkv + (size_t)(kv0 + voct * 8) * QKV + 2 * D + h * HD + 2 * vp2;
            bf16x8 r0, r1;
#pragma unroll
            for (int j = 0; j < 8; ++j) {
                const unsigned u = *(const unsigned*)(vp + (size_t)j * QKV);
                unsigned short us0 = (unsigned short)(u & 0xffff);
                unsigned short us1 = (unsigned short)(u >> 16);
                r0[j] = *(const bf16*)&us0;
                r1[j] = *(const bf16*)&us1;
            }
            *(bf16x8*)&Vs[(2 * vp2) * 72 + voct * 8]     = r0;
            *(bf16x8*)&Vs[(2 * vp2 + 1) * 72 + voct * 8] = r1;
        }
        __syncthreads();

        if (kv0 <= qbase + 15) {
            f32x4 c[4];
#pragma unroll
            for (int j = 0; j < 4; ++j) c[j] = (f32x4){0.f, 0.f, 0.f, 0.f};
            __builtin_amdgcn_s_setprio(1);
#pragma unroll
            for (int ds = 0; ds < 4; ++ds) {
#pragma unroll
                for (int j = 0; j < 4; ++j) {
                    const int r = j * 16 + lo;
                    bf16x8 b = *(const bf16x8*)&Ks[(r * 128 + ds * 32 + hi * 8) ^ ((r & 7) << 3)];
                    c[j] = __builtin_amdgcn_mfma_f32_16x16x32_bf16(qfrag[ds], b, c[j], 0, 0, 0);
                }
            }
            __builtin_amdgcn_s_setprio(0);
#pragma unroll
            for (int r = 0; r < 4; ++r) {
                const int q = qbase + hi * 4 + r;
                float s[4];
#pragma unroll
                for (int j = 0; j < 4; ++j) {
                    const int ki = kv0 + j * 16 + lo;
                    s[j] = c[j][r] * scale + slope * (float)(ki - (S - 1));
                    if (ki > q) s[j] = -1e30f;
                }
                float tm = fmaxf(fmaxf(s[0], s[1]), fmaxf(s[2], s[3]));
                tm = fmaxf(tm, __shfl_xor(tm, 1));
                tm = fmaxf(tm, __shfl_xor(tm, 2));
                tm = fmaxf(tm, __shfl_xor(tm, 4));
                tm = fmaxf(tm, __shfl_xor(tm, 8));
                const float mnew = fmaxf(mrow[r], tm);
                const float cr = __expf(mrow[r] - mnew);
                float p[4], ps = 0.f;
#pragma unroll
                for (int j = 0; j < 4; ++j) { p[j] = __expf(s[j] - mnew); ps += p[j]; }
                ps += __shfl_xor(ps, 1);
                ps += __shfl_xor(ps, 2);
                ps += __shfl_xor(ps, 4);
                ps += __shfl_xor(ps, 8);
                lrow[r] = lrow[r] * cr + ps;
                mrow[r] = mnew;
#pragma unroll
                for (int dt = 0; dt < 8; ++dt) o[dt][r] *= cr;
#pragma unroll
                for (int j = 0; j < 4; ++j)
                    Ps[w * 1152 + (hi * 4 + r) * 72 + j * 16 + lo] = (bf16)p[j];
            }
            bf16x8 pa0 = *(const bf16x8*)&Ps[w * 1152 + lo * 72 + hi * 8];
            bf16x8 pa1 = *(const bf16x8*)&Ps[w * 1152 + lo * 72 + 32 + hi * 8];
            __builtin_amdgcn_s_setprio(1);
#pragma unroll
            for (int dt = 0; dt < 8; ++dt) {
                bf16x8 bv0 = *(const bf16x8*)&Vs[(dt * 16 + lo) * 72 + hi * 8];
                bf16x8 bv1 = *(const bf16x8*)&Vs[(dt * 16 + lo) * 72 + 32 + hi * 8];
                o[dt] = __builtin_amdgcn_mfma_f32_16x16x32_bf16(pa0, bv0, o[dt], 0, 0, 0);
                o[dt] = __builtin_amdgcn_mfma_f32_16x16x32_bf16(pa1, bv1, o[dt], 0, 0, 0);
            }
            __builtin_amdgcn_s_setprio(0);
        }
        __syncthreads();
    }

#pragma unroll
    for (int r = 0; r < 4; ++r) {
        const float inv = 1.0f / lrow[r];
        const int q = qbase + hi * 4 + r;
        bf16* op = attn_out + (size_t)q * D + h * HD;
#pragma unroll
        for (int dt = 0; dt < 8; ++dt)
            op[dt * 16 + lo] = (bf16)(o[dt][r] * inv);
    }
}

extern "C" void kernel_launch(void* const* d_in, const int* in_sizes, int n_in,
                              void* d_out, int out_size, void* d_ws, size_t ws_size,
                              hipStream_t stream) {
    const int S = 2048, D = 4096, QKV = 12288;
    const int NH = 6144;
    const float* x     = (const float*)d_in[0];
    const float* w_qkv = (const float*)d_in[1];
    const float* b_qkv = (const float*)d_in[2];
    const float* w_out = (const float*)d_in[3];
    const float* b_out = (const float*)d_in[4];
    float* out = (float*)d_out;

    char* ws = (char*)d_ws;
    const size_t need_full = (size_t)S * D * 2 + (size_t)QKV * D * 2 + (size_t)S * QKV * 2;

    if (ws_size >= need_full) {
        // full-weight path: one QKV GEMM launch (96x16 = 1536 blocks of 128^2)
        bf16* xb    = (bf16*)ws;                                    // [2048][4096]
        bf16* attnb = xb;                                           // reuse after xb dead
        bf16* wqb   = (bf16*)(ws + (size_t)S * D * 2);              // [12288][4096]
        bf16* wob   = wqb;                                          // reuse after wqb dead
        bf16* qkvb  = (bf16*)(ws + (size_t)S * D * 2 + (size_t)QKV * D * 2);  // [2048][12288]

        cvt_f32_bf16<<<2048, 256, 0, stream>>>(x, xb, S * D / 16);
        cvt_f32_bf16<<<4096, 256, 0, stream>>>(w_qkv, wqb, QKV * D / 16);
        gemm_glds<1><<<dim3(QKV / 128, S / 128), 256, 0, stream>>>(xb, wqb, b_qkv, qkvb, D, QKV);
        attn_mfma<<<512, 512, 0, stream>>>(qkvb, attnb);
        cvt_f32_bf16<<<2048, 256, 0, stream>>>(w_out, wob, D * D / 16);
        gemm_glds<0><<<dim3(D / 128, S / 128), 256, 0, stream>>>(attnb, wob, b_out, out, D, D);
    } else {
        // halves path (peak 117.4 MB)
        bf16* xb    = (bf16*)ws;
        bf16* attnb = xb;
        bf16* wb    = (bf16*)(ws + (size_t)S * D * 2);              // [6144][4096]
        bf16* wob   = wb;
        bf16* qkvb  = (bf16*)(ws + (size_t)S * D * 2 + (size_t)NH * D * 2);

        cvt_f32_bf16<<<2048, 256, 0, stream>>>(x, xb, S * D / 16);
        cvt_f32_bf16<<<2048, 256, 0, stream>>>(w_qkv, wb, NH * D / 16);
        gemm_glds<1><<<dim3(NH / 128, S / 128), 256, 0, stream>>>(xb, wb, b_qkv, qkvb, D, QKV);
        cvt_f32_bf16<<<2048, 256, 0, stream>>>(w_qkv + (size_t)NH * D, wb, NH * D / 16);
        gemm_glds<1><<<dim3(NH / 128, S / 128), 256, 0, stream>>>(xb, wb, b_qkv + NH, qkvb + NH, D, QKV);
        attn_mfma<<<512, 512, 0, stream>>>(qkvb, attnb);
        cvt_f32_bf16<<<2048, 256, 0, stream>>>(w_out, wob, D * D / 16);
        gemm_glds<0><<<dim3(D / 128, S / 128), 256, 0, stream>>>(attnb, wob, b_out, out, D, D);
    }
}

// Round 7
// 459.895 us; speedup vs baseline: 1.4078x; 1.0531x over previous
//
#include <hip/hip_runtime.h>
#include <hip/hip_bf16.h>

typedef __bf16 bf16;
typedef __attribute__((ext_vector_type(8))) __bf16 bf16x8;
typedef __attribute__((ext_vector_type(4))) float f32x4;

#define GLOAD_LDS16(g, l)                                                        \
    __builtin_amdgcn_global_load_lds(                                            \
        (const __attribute__((address_space(1))) void*)(g),                      \
        (__attribute__((address_space(3))) void*)(l), 16, 0, 0)

#define WAITV(n) asm volatile("s_waitcnt vmcnt(" #n ")" ::: "memory")
#define LGKM0()  asm volatile("s_waitcnt lgkmcnt(0)" ::: "memory")
#define BAR()    __builtin_amdgcn_s_barrier()

// ---------------- fp32 -> bf16 conversion (vectorized, grid-stride) ----------------
__global__ __launch_bounds__(256) void cvt_f32_bf16(
    const float* __restrict__ src, bf16* __restrict__ dst, int n16)
{
    int idx = blockIdx.x * 256 + threadIdx.x;
    const int stride = gridDim.x * 256;
    for (int i = idx; i < n16; i += stride) {
        const float* p = src + (size_t)i * 16;
        f32x4 a = *(const f32x4*)p;
        f32x4 b = *(const f32x4*)(p + 4);
        f32x4 c = *(const f32x4*)(p + 8);
        f32x4 d = *(const f32x4*)(p + 12);
        bf16x8 h0, h1;
#pragma unroll
        for (int j = 0; j < 4; ++j) {
            h0[j] = (bf16)a[j]; h0[4 + j] = (bf16)b[j];
            h1[j] = (bf16)c[j]; h1[4 + j] = (bf16)d[j];
        }
        bf16* q = dst + (size_t)i * 16;
        *(bf16x8*)q = h0;
        *(bf16x8*)(q + 8) = h1;
    }
}

// ---- 4-phase pipelined GEMM: C[M][N] = A[M][K]*B[N][K]^T + bias ----
// BM=256, BN=128, BK=64, 8 waves (512 thr). LDS: 2 K-tile buffers x {A0(128x64), A1(128x64),
// B(128x64)} = 96KB. Per phase: {ds_read frags || issue 1 stage-unit} bar lgkm0 {16 MFMA} vmcnt(6) bar.
// Stage-unit issue schedule (slot-death verified): ph1: A1[t+1]; ph2: A0,B[t+2]; ph3: A1[t+2];
// ph4: A0,B[t+3]. Steady vmcnt(6) = 3 units x 2 loads in flight; tail drains 6->2->0.
// Swizzle (verified 0-conflict r6): phys 16B-slot s of row r holds chunk s^(r&7); staged via
// pre-swizzled global col; read slot (kk*4+hi)^(lo&7).
template <int OUT_BF16>
__global__ __launch_bounds__(512, 2) void gemm_pipe(
    const bf16* __restrict__ A, const bf16* __restrict__ B,
    const float* __restrict__ bias, void* __restrict__ Cout,
    int K, int ldc, int nbx)
{
    __shared__ bf16 lds[2][384 * 64];   // per buf: [0,128*64)=A0, [128*64,256*64)=A1, [256*64,384*64)=B

    // XCD-chunked bijective swizzle (gridDim.x % 8 == 0 for all our grids)
    const int nwg = gridDim.x;
    const int cpx = nwg >> 3;
    const int swz = ((int)blockIdx.x & 7) * cpx + ((int)blockIdx.x >> 3);
    const int bx = swz % nbx, by = swz / nbx;
    const int brow = by * 256, bcol = bx * 128;

    const int tid  = threadIdx.x;
    const int wv   = tid >> 6, lane = tid & 63;
    const int lo   = lane & 15, hi = lane >> 4;
    const int wrp  = wv >> 2, wcp = wv & 3;      // per-phase wave grid: 2(M) x 4(N) over 128x128

    const int srow = lane >> 3;                       // row-in-chunk 0..7
    const int scol = ((lane & 7) ^ (lane >> 3)) * 8;  // pre-swizzled global col (elems)

    f32x4 accH0[4][2], accH1[4][2];
#pragma unroll
    for (int m = 0; m < 4; ++m)
#pragma unroll
        for (int n = 0; n < 2; ++n) {
            accH0[m][n] = (f32x4){0.f, 0.f, 0.f, 0.f};
            accH1[m][n] = (f32x4){0.f, 0.f, 0.f, 0.f};
        }

    // stage one 16KB unit (128 rows x 64 k) of tile t; unit: 0=A rows 0-127, 1=A rows 128-255, 2=B
    auto STAGE = [&](int t, int unit) {
        const int k0 = t * 64;
        bf16* lb = &lds[t & 1][unit * (128 * 64)];
        const bf16* gb = (unit == 2) ? (B + (size_t)bcol * K + k0)
                                     : (A + (size_t)(brow + unit * 128) * K + k0);
#pragma unroll
        for (int j = 0; j < 2; ++j) {
            const int c = wv * 2 + j;    // chunk: 8 rows, wave-uniform LDS base + lane*16
            GLOAD_LDS16(gb + (size_t)(c * 8 + srow) * K + scol, lb + c * 512);
        }
    };

    bf16x8 af[4][2], bfr[2][2];
    auto LOADB = [&](int b) {
#pragma unroll
        for (int n = 0; n < 2; ++n) {
            const int rb = wcp * 32 + n * 16 + lo;
#pragma unroll
            for (int kk = 0; kk < 2; ++kk)
                bfr[n][kk] = *(const bf16x8*)&lds[b][256 * 64 + rb * 64 + (((kk * 4 + hi) ^ (lo & 7)) * 8)];
        }
    };
    auto LOADA = [&](int b, int half) {
#pragma unroll
        for (int m = 0; m < 4; ++m) {
            const int ru = wrp * 64 + m * 16 + lo;
#pragma unroll
            for (int kk = 0; kk < 2; ++kk)
                af[m][kk] = *(const bf16x8*)&lds[b][half * (128 * 64) + ru * 64 + (((kk * 4 + hi) ^ (lo & 7)) * 8)];
        }
    };
    auto MFMA16 = [&](f32x4 (&acc)[4][2]) {
        __builtin_amdgcn_s_setprio(1);
#pragma unroll
        for (int m = 0; m < 4; ++m)
#pragma unroll
            for (int n = 0; n < 2; ++n)
#pragma unroll
                for (int kk = 0; kk < 2; ++kk)
                    acc[m][n] = __builtin_amdgcn_mfma_f32_16x16x32_bf16(af[m][kk], bfr[n][kk], acc[m][n], 0, 0, 0);
        __builtin_amdgcn_s_setprio(0);
    };

    const int nt = K / 64, niter = nt / 2;   // 64 tiles, 32 iterations for K=4096

    // prologue: A0[0],B[0],A1[0],A0[1],B[1] (10 loads); need oldest 4 -> vmcnt(6)
    STAGE(0, 0); STAGE(0, 2); STAGE(0, 1); STAGE(1, 0); STAGE(1, 2);
    WAITV(6); BAR();

    for (int it = 0; it < niter; ++it) {
        const int t0 = 2 * it;
        const bool nl = (it + 1 < niter);

        // ---- phase 1: tile t0 (buf0), rows 0-127 ----
        LOADB(0); LOADA(0, 0);
        STAGE(t0 + 1, 1);                    // A1[t0+1] -> buf1 (slot dead since prev ph4)
        BAR(); LGKM0();
        MFMA16(accH0);
        WAITV(6); BAR();                     // confirm A1[t0]

        // ---- phase 2: tile t0, rows 128-255 ----
        LOADA(0, 1);
        if (nl) { STAGE(t0 + 2, 0); STAGE(t0 + 2, 2); }   // A0,B[t0+2] -> buf0 (read done ph1)
        BAR(); LGKM0();
        MFMA16(accH1);
        if (nl) WAITV(6); else WAITV(2);     // confirm A0,B[t0+1]
        BAR();

        // ---- phase 3: tile t0+1 (buf1), rows 0-127 ----
        LOADB(1); LOADA(1, 0);
        if (nl) STAGE(t0 + 2, 1);            // A1[t0+2] -> buf0 (read done ph2)
        BAR(); LGKM0();
        MFMA16(accH0);
        if (nl) WAITV(6); else WAITV(0);     // confirm A1[t0+1]
        BAR();

        // ---- phase 4: tile t0+1, rows 128-255 ----
        LOADA(1, 1);
        if (nl) { STAGE(t0 + 3, 0); STAGE(t0 + 3, 2); }   // A0,B[t0+3] -> buf1 (read done ph3)
        BAR(); LGKM0();
        MFMA16(accH1);
        if (nl) { WAITV(6); BAR(); }         // confirm A0,B[t0+2]
    }

    // epilogue: C/D layout row=(lane>>4)*4+r, col=lane&15
    auto EPI = [&](f32x4 (&acc)[4][2], int half) {
#pragma unroll
        for (int m = 0; m < 4; ++m) {
            const int row = brow + half * 128 + wrp * 64 + m * 16 + hi * 4;
#pragma unroll
            for (int n = 0; n < 2; ++n) {
                const int col = bcol + wcp * 32 + n * 16 + lo;
                const float bv = bias[col];
#pragma unroll
                for (int r = 0; r < 4; ++r) {
                    const float v = acc[m][n][r] + bv;
                    if (OUT_BF16)
                        ((bf16*)Cout)[(size_t)(row + r) * ldc + col] = (bf16)v;
                    else
                        ((float*)Cout)[(size_t)(row + r) * ldc + col] = v;
                }
            }
        }
    };
    EPI(accH0, 0);
    EPI(accH1, 1);
}

// ---------------- MFMA flash attention: causal + ALiBi, bf16 in/out (round-6, verified) ----------------
__global__ __launch_bounds__(512) void attn_mfma(
    const bf16* __restrict__ qkv, bf16* __restrict__ attn_out)
{
    const int S = 2048, QKV = 12288, D = 4096, HD = 128;
    const int bid = blockIdx.x;
    const int h   = bid & 31;
    const int qi  = 15 - (bid >> 5);
    const int q0  = qi * 128;
    const int tid = threadIdx.x;
    const int w    = tid >> 6, lane = tid & 63;
    const int lo   = lane & 15, hi = lane >> 4;
    const int qbase = q0 + w * 16;

    __shared__ bf16 Ks[64 * 128];
    __shared__ bf16 Vs[128 * 72];
    __shared__ bf16 Ps[8 * 16 * 72];

    const float scale = 0.08838834764831845f;
    const float slope = exp2f(-0.25f * (float)(h + 1));

    bf16x8 qfrag[4];
#pragma unroll
    for (int ds = 0; ds < 4; ++ds)
        qfrag[ds] = *(const bf16x8*)(qkv + (size_t)(qbase + lo) * QKV + h * HD + ds * 32 + hi * 8);

    f32x4 o[8];
#pragma unroll
    for (int dt = 0; dt < 8; ++dt) o[dt] = (f32x4){0.f, 0.f, 0.f, 0.f};
    float mrow[4] = {-1e30f, -1e30f, -1e30f, -1e30f};
    float lrow[4] = {0.f, 0.f, 0.f, 0.f};

    const int krow = tid >> 3;
    const int kch  = tid & 7;
    const int vp2  = tid & 63;
    const int voct = tid >> 6;

    const int ntile = (q0 + 128) / 64;
    for (int t = 0; t < ntile; ++t) {
        const int kv0 = t * 64;
        {
            const bf16* kp = qkv + (size_t)(kv0 + krow) * QKV + D + h * HD + kch * 16;
            bf16x8 k0 = *(const bf16x8*)kp;
            bf16x8 k1 = *(const bf16x8*)(kp + 8);
            const int kb  = krow * 128 + kch * 16;
            const int swz = (krow & 7) << 3;
            *(bf16x8*)&Ks[kb ^ swz]       = k0;
            *(bf16x8*)&Ks[(kb + 8) ^ swz] = k1;
        }
        {
            const bf16* vp = qkv + (size_t)(kv0 + voct * 8) * QKV + 2 * D + h * HD + 2 * vp2;
            bf16x8 r0, r1;
#pragma unroll
            for (int j = 0; j < 8; ++j) {
                const unsigned u = *(const unsigned*)(vp + (size_t)j * QKV);
                unsigned short us0 = (unsigned short)(u & 0xffff);
                unsigned short us1 = (unsigned short)(u >> 16);
                r0[j] = *(const bf16*)&us0;
                r1[j] = *(const bf16*)&us1;
            }
            *(bf16x8*)&Vs[(2 * vp2) * 72 + voct * 8]     = r0;
            *(bf16x8*)&Vs[(2 * vp2 + 1) * 72 + voct * 8] = r1;
        }
        __syncthreads();

        if (kv0 <= qbase + 15) {
            f32x4 c[4];
#pragma unroll
            for (int j = 0; j < 4; ++j) c[j] = (f32x4){0.f, 0.f, 0.f, 0.f};
            __builtin_amdgcn_s_setprio(1);
#pragma unroll
            for (int ds = 0; ds < 4; ++ds) {
#pragma unroll
                for (int j = 0; j < 4; ++j) {
                    const int r = j * 16 + lo;
                    bf16x8 b = *(const bf16x8*)&Ks[(r * 128 + ds * 32 + hi * 8) ^ ((r & 7) << 3)];
                    c[j] = __builtin_amdgcn_mfma_f32_16x16x32_bf16(qfrag[ds], b, c[j], 0, 0, 0);
                }
            }
            __builtin_amdgcn_s_setprio(0);
#pragma unroll
            for (int r = 0; r < 4; ++r) {
                const int q = qbase + hi * 4 + r;
                float s[4];
#pragma unroll
                for (int j = 0; j < 4; ++j) {
                    const int ki = kv0 + j * 16 + lo;
                    s[j] = c[j][r] * scale + slope * (float)(ki - (S - 1));
                    if (ki > q) s[j] = -1e30f;
                }
                float tm = fmaxf(fmaxf(s[0], s[1]), fmaxf(s[2], s[3]));
                tm = fmaxf(tm, __shfl_xor(tm, 1));
                tm = fmaxf(tm, __shfl_xor(tm, 2));
                tm = fmaxf(tm, __shfl_xor(tm, 4));
                tm = fmaxf(tm, __shfl_xor(tm, 8));
                const float mnew = fmaxf(mrow[r], tm);
                const float cr = __expf(mrow[r] - mnew);
                float p[4], ps = 0.f;
#pragma unroll
                for (int j = 0; j < 4; ++j) { p[j] = __expf(s[j] - mnew); ps += p[j]; }
                ps += __shfl_xor(ps, 1);
                ps += __shfl_xor(ps, 2);
                ps += __shfl_xor(ps, 4);
                ps += __shfl_xor(ps, 8);
                lrow[r] = lrow[r] * cr + ps;
                mrow[r] = mnew;
#pragma unroll
                for (int dt = 0; dt < 8; ++dt) o[dt][r] *= cr;
#pragma unroll
                for (int j = 0; j < 4; ++j)
                    Ps[w * 1152 + (hi * 4 + r) * 72 + j * 16 + lo] = (bf16)p[j];
            }
            bf16x8 pa0 = *(const bf16x8*)&Ps[w * 1152 + lo * 72 + hi * 8];
            bf16x8 pa1 = *(const bf16x8*)&Ps[w * 1152 + lo * 72 + 32 + hi * 8];
            __builtin_amdgcn_s_setprio(1);
#pragma unroll
            for (int dt = 0; dt < 8; ++dt) {
                bf16x8 bv0 = *(const bf16x8*)&Vs[(dt * 16 + lo) * 72 + hi * 8];
                bf16x8 bv1 = *(const bf16x8*)&Vs[(dt * 16 + lo) * 72 + 32 + hi * 8];
                o[dt] = __builtin_amdgcn_mfma_f32_16x16x32_bf16(pa0, bv0, o[dt], 0, 0, 0);
                o[dt] = __builtin_amdgcn_mfma_f32_16x16x32_bf16(pa1, bv1, o[dt], 0, 0, 0);
            }
            __builtin_amdgcn_s_setprio(0);
        }
        __syncthreads();
    }

#pragma unroll
    for (int r = 0; r < 4; ++r) {
        const float inv = 1.0f / lrow[r];
        const int q = qbase + hi * 4 + r;
        bf16* op = attn_out + (size_t)q * D + h * HD;
#pragma unroll
        for (int dt = 0; dt < 8; ++dt)
            op[dt * 16 + lo] = (bf16)(o[dt][r] * inv);
    }
}

extern "C" void kernel_launch(void* const* d_in, const int* in_sizes, int n_in,
                              void* d_out, int out_size, void* d_ws, size_t ws_size,
                              hipStream_t stream) {
    const int S = 2048, D = 4096, QKV = 12288;
    const int NH = 6144;
    const float* x     = (const float*)d_in[0];
    const float* w_qkv = (const float*)d_in[1];
    const float* b_qkv = (const float*)d_in[2];
    const float* w_out = (const float*)d_in[3];
    const float* b_out = (const float*)d_in[4];
    float* out = (float*)d_out;

    char* ws = (char*)d_ws;
    const size_t need_full = (size_t)S * D * 2 + (size_t)QKV * D * 2 + (size_t)S * QKV * 2;

    if (ws_size >= need_full) {
        // full-weight path: QKV one launch; 768 blocks = 3 exact CU rounds; out-proj 256 = 1 round
        bf16* xb    = (bf16*)ws;                                    // [2048][4096]
        bf16* attnb = xb;                                           // reuse after xb dead
        bf16* wqb   = (bf16*)(ws + (size_t)S * D * 2);              // [12288][4096]
        bf16* wob   = wqb;                                          // reuse after wqb dead
        bf16* qkvb  = (bf16*)(ws + (size_t)S * D * 2 + (size_t)QKV * D * 2);  // [2048][12288]

        cvt_f32_bf16<<<2048, 256, 0, stream>>>(x, xb, S * D / 16);
        cvt_f32_bf16<<<4096, 256, 0, stream>>>(w_qkv, wqb, QKV * D / 16);
        gemm_pipe<1><<<(QKV / 128) * (S / 256), 512, 0, stream>>>(xb, wqb, b_qkv, qkvb, D, QKV, QKV / 128);
        attn_mfma<<<512, 512, 0, stream>>>(qkvb, attnb);
        cvt_f32_bf16<<<2048, 256, 0, stream>>>(w_out, wob, D * D / 16);
        gemm_pipe<0><<<(D / 128) * (S / 256), 512, 0, stream>>>(attnb, wob, b_out, out, D, D, D / 128);
    } else {
        // halves path (peak 117.4 MB)
        bf16* xb    = (bf16*)ws;
        bf16* attnb = xb;
        bf16* wb    = (bf16*)(ws + (size_t)S * D * 2);              // [6144][4096]
        bf16* wob   = wb;
        bf16* qkvb  = (bf16*)(ws + (size_t)S * D * 2 + (size_t)NH * D * 2);

        cvt_f32_bf16<<<2048, 256, 0, stream>>>(x, xb, S * D / 16);
        cvt_f32_bf16<<<2048, 256, 0, stream>>>(w_qkv, wb, NH * D / 16);
        gemm_pipe<1><<<(NH / 128) * (S / 256), 512, 0, stream>>>(xb, wb, b_qkv, qkvb, D, QKV, NH / 128);
        cvt_f32_bf16<<<2048, 256, 0, stream>>>(w_qkv + (size_t)NH * D, wb, NH * D / 16);
        gemm_pipe<1><<<(NH / 128) * (S / 256), 512, 0, stream>>>(xb, wb, b_qkv + NH, qkvb + NH, D, QKV, NH / 128);
        attn_mfma<<<512, 512, 0, stream>>>(qkvb, attnb);
        cvt_f32_bf16<<<2048, 256, 0, stream>>>(w_out, wob, D * D / 16);
        gemm_pipe<0><<<(D / 128) * (S / 256), 512, 0, stream>>>(attnb, wob, b_out, out, D, D, D / 128);
    }
}